// Round 3
// baseline (484.314 us; speedup 1.0000x reference)
//
#include <hip/hip_runtime.h>
#include <hip/hip_bf16.h>

#define SPAT 32768   // 32*32*32
#define BATCH 2
#define GN_EPS 1e-5f

// ---------------- 1x1x1 conv (channel GEMM) + optional affine + optional relu ----
// out[(b*Cout+o)*S + s] = act( affine( sum_c w[o*Cin+c] * in[(b*Cin+c)*S + s] ) )
template <bool RELU, bool AFF>
__global__ void k_c1(const float* __restrict__ in, const float* __restrict__ w,
                     const float* __restrict__ sc, const float* __restrict__ bi,
                     float* __restrict__ out, int Cin, int Cout)
{
    int s = blockIdx.x * blockDim.x + threadIdx.x;
    int o = blockIdx.y, b = blockIdx.z;
    const float* ip = in + (size_t)b * Cin * SPAT + s;
    const float* wp = w + (size_t)o * Cin;
    float acc = 0.f;
#pragma unroll 8
    for (int c = 0; c < Cin; ++c)
        acc = fmaf(wp[c], ip[(size_t)c * SPAT], acc);
    if (AFF) acc = acc * sc[o] + bi[o];
    else     acc = acc + bi[o];               // cv4: bias only
    if (RELU) acc = fmaxf(acc, 0.f);
    out[((size_t)b * Cout + o) * SPAT + s] = acc;
}

// ---------------- depthwise 5x5x5, zero pad 2, + affine ----------------
__global__ void k_dw5(const float* __restrict__ in, const float* __restrict__ w2,
                      const float* __restrict__ s2, const float* __restrict__ b2,
                      float* __restrict__ out)
{
    int s = blockIdx.x * blockDim.x + threadIdx.x;
    int c = blockIdx.y, b = blockIdx.z;
    int d = s >> 10, h = (s >> 5) & 31, wq = s & 31;
    const float* ip = in + ((size_t)(b * 32 + c)) * SPAT;
    const float* wp = w2 + c * 125;
    float acc = 0.f;
    for (int kd = 0; kd < 5; ++kd) {
        int zd = d + kd - 2; if (zd < 0 || zd > 31) continue;
        for (int kh = 0; kh < 5; ++kh) {
            int zh = h + kh - 2; if (zh < 0 || zh > 31) continue;
#pragma unroll
            for (int kw = 0; kw < 5; ++kw) {
                int zw = wq + kw - 2; if (zw < 0 || zw > 31) continue;
                acc = fmaf(wp[kd * 25 + kh * 5 + kw],
                           ip[zd * 1024 + zh * 32 + zw], acc);
            }
        }
    }
    acc = acc * s2[c] + b2[c];
    out[((size_t)(b * 32 + c)) * SPAT + s] = acc;
}

// ---------------- GroupNorm stats, stage 1: per-chunk partial sums ----------------
// grid: (54 chunks, 16 bg); each block reduces 16384 contiguous floats.
__global__ void k_gn_part(const float* __restrict__ wk, float* __restrict__ partial)
{
    int bg = blockIdx.y;
    const float* p = wk + (size_t)bg * 27 * SPAT + (size_t)blockIdx.x * 16384;
    float sum = 0.f, ss = 0.f;
    for (int i = threadIdx.x; i < 16384; i += 256) {
        float v = p[i];
        sum += v; ss += v * v;
    }
    __shared__ float sh[512];
    sh[threadIdx.x] = sum; sh[256 + threadIdx.x] = ss;
    __syncthreads();
    for (int off = 128; off > 0; off >>= 1) {
        if (threadIdx.x < off) {
            sh[threadIdx.x] += sh[threadIdx.x + off];
            sh[256 + threadIdx.x] += sh[256 + threadIdx.x + off];
        }
        __syncthreads();
    }
    if (threadIdx.x == 0) {
        partial[(bg * 54 + blockIdx.x) * 2 + 0] = sh[0];
        partial[(bg * 54 + blockIdx.x) * 2 + 1] = sh[256];
    }
}

// ---------------- GroupNorm stats, stage 2: reduce 54 partials per bg ----------------
__global__ void k_gn_final(const float* __restrict__ partial, float* __restrict__ stats)
{
    int bg = blockIdx.x;
    int t = threadIdx.x;
    float sum = 0.f, ss = 0.f;
    if (t < 54) {
        sum = partial[(bg * 54 + t) * 2 + 0];
        ss  = partial[(bg * 54 + t) * 2 + 1];
    }
#pragma unroll
    for (int off = 32; off > 0; off >>= 1) {
        sum += __shfl_down(sum, off, 64);
        ss  += __shfl_down(ss,  off, 64);
    }
    if (t == 0) {
        stats[bg * 2 + 0] = sum;
        stats[bg * 2 + 1] = ss;
    }
}

// ---------------- SKA: 27 circular-shifted taps of x * normalized wk ----------------
__global__ void k_ska(const float* __restrict__ x, const float* __restrict__ wk,
                      const float* __restrict__ stats,
                      const float* __restrict__ gn_g, const float* __restrict__ gn_b,
                      const float* __restrict__ bn_s, const float* __restrict__ bn_b,
                      float* __restrict__ y)
{
    int s = blockIdx.x * blockDim.x + threadIdx.x;
    int c = blockIdx.y, b = blockIdx.z;
    int g = c >> 3;
    int bg = b * 8 + g;
    const float N = 27.f * (float)SPAT;
    float mu  = stats[bg * 2 + 0] / N;
    float var = stats[bg * 2 + 1] / N - mu * mu;
    float inv = rsqrtf(var + GN_EPS);
    int d = s >> 10, h = (s >> 5) & 31, wq = s & 31;
    const float* xp = x + ((size_t)(b * 64 + c)) * SPAT;
    const float* wp = wk + ((size_t)(b * 216 + g * 27)) * SPAT + s;
    float acc = 0.f;
    int k = 0;
    for (int di = -1; di <= 1; ++di) {
        int zd = (d + di) & 31;
        for (int hi = -1; hi <= 1; ++hi) {
            int zh = (h + hi) & 31;
#pragma unroll
            for (int wi = -1; wi <= 1; ++wi, ++k) {
                int zw = (wq + wi) & 31;
                float xv = xp[zd * 1024 + zh * 32 + zw];
                float wn = (wp[(size_t)k * SPAT] - mu) * inv * gn_g[g * 27 + k]
                           + gn_b[g * 27 + k];
                acc = fmaf(xv, wn, acc);
            }
        }
    }
    float xv0 = xp[s];
    y[((size_t)(b * 64 + c)) * SPAT + s] = acc * bn_s[c] + bn_b[c] + xv0;
}

// ---------------- pw2 (128->64) + affine + residual -> fp32 out ----------------
__global__ void k_pw2_out(const float* __restrict__ f1, const float* __restrict__ w,
                          const float* __restrict__ sc, const float* __restrict__ bi,
                          const float* __restrict__ y, float* __restrict__ out)
{
    int s = blockIdx.x * blockDim.x + threadIdx.x;
    int o = blockIdx.y, b = blockIdx.z;
    const float* ip = f1 + (size_t)b * 128 * SPAT + s;
    const float* wp = w + o * 128;
    float acc = 0.f;
#pragma unroll 8
    for (int c = 0; c < 128; ++c)
        acc = fmaf(wp[c], ip[(size_t)c * SPAT], acc);
    acc = acc * sc[o] + bi[o] + y[((size_t)(b * 64 + o)) * SPAT + s];
    out[((size_t)(b * 64 + o)) * SPAT + s] = acc;
}

extern "C" void kernel_launch(void* const* d_in, const int* in_sizes, int n_in,
                              void* d_out, int out_size, void* d_ws, size_t ws_size,
                              hipStream_t stream)
{
    const float* x     = (const float*)d_in[0];
    const float* w1    = (const float*)d_in[1];
    const float* s1    = (const float*)d_in[2];
    const float* b1    = (const float*)d_in[3];
    const float* w2    = (const float*)d_in[4];
    const float* s2    = (const float*)d_in[5];
    const float* b2    = (const float*)d_in[6];
    const float* w3    = (const float*)d_in[7];
    const float* s3    = (const float*)d_in[8];
    const float* b3    = (const float*)d_in[9];
    const float* w4    = (const float*)d_in[10];
    const float* b4    = (const float*)d_in[11];
    const float* gn_g  = (const float*)d_in[12];
    const float* gn_b  = (const float*)d_in[13];
    const float* bn_s  = (const float*)d_in[14];
    const float* bn_b  = (const float*)d_in[15];
    const float* pw1_w = (const float*)d_in[16];
    const float* pw1_s = (const float*)d_in[17];
    const float* pw1_b = (const float*)d_in[18];
    const float* pw2_w = (const float*)d_in[19];
    const float* pw2_s = (const float*)d_in[20];
    const float* pw2_b = (const float*)d_in[21];

    // Overlapped workspace layout (total ~18.4M floats = 73.4 MB):
    //   region A (4.19M): [a1 | a2] during LKP, then y during SKA/FFN
    //   region B (14.16M): wk during cv4..ska, then f1 during FFN
    float* ws    = (float*)d_ws;
    float* a1    = ws;                                   // 2*32*S
    float* a2    = a1 + (size_t)BATCH * 32 * SPAT;       // 2*32*S
    float* yb    = ws;                                   // 2*64*S (over a1+a2)
    float* wkb   = ws + (size_t)BATCH * 64 * SPAT;       // 2*216*S
    float* f1    = wkb;                                  // 2*128*S (over wk)
    float* part  = wkb + (size_t)BATCH * 216 * SPAT;     // 16*54*2
    float* stats = part + 16 * 54 * 2;                   // 32

    dim3 blk(256);
    // cv1 + BN + ReLU : 64 -> 32
    k_c1<true, true><<<dim3(SPAT / 256, 32, BATCH), blk, 0, stream>>>(
        x, w1, s1, b1, a1, 64, 32);
    // dw 5^3 + BN
    k_dw5<<<dim3(SPAT / 256, 32, BATCH), blk, 0, stream>>>(a1, w2, s2, b2, a2);
    // cv3 + BN + ReLU : 32 -> 32 (into a1)
    k_c1<true, true><<<dim3(SPAT / 256, 32, BATCH), blk, 0, stream>>>(
        a2, w3, s3, b3, a1, 32, 32);
    // cv4 + bias : 32 -> 216
    k_c1<false, false><<<dim3(SPAT / 256, 216, BATCH), blk, 0, stream>>>(
        a1, w4, (const float*)nullptr, b4, wkb, 32, 216);
    // GroupNorm stats (two-stage, deterministic)
    k_gn_part<<<dim3(54, 16, 1), blk, 0, stream>>>(wkb, part);
    k_gn_final<<<dim3(16, 1, 1), dim3(64), 0, stream>>>(part, stats);
    // SKA + BN + residual -> y (over a1/a2, which are dead now)
    k_ska<<<dim3(SPAT / 256, 64, BATCH), blk, 0, stream>>>(
        x, wkb, stats, gn_g, gn_b, bn_s, bn_b, yb);
    // pw1 + BN + ReLU : 64 -> 128 (f1 over wk, which is dead now)
    k_c1<true, true><<<dim3(SPAT / 256, 128, BATCH), blk, 0, stream>>>(
        yb, pw1_w, pw1_s, pw1_b, f1, 64, 128);
    // pw2 + BN + residual -> out (fp32)
    k_pw2_out<<<dim3(SPAT / 256, 64, BATCH), blk, 0, stream>>>(
        f1, pw2_w, pw2_s, pw2_b, yb, (float*)d_out);
}

// Round 4
// 249.990 us; speedup vs baseline: 1.9373x; 1.9373x over previous
//
#include <hip/hip_runtime.h>
#include <hip/hip_bf16.h>

#define SPAT 32768   // 32*32*32
#define BATCH 2
#define GN_EPS 1e-5f

__device__ __forceinline__ void fma4(float4& a, const float4& v, float w) {
    a.x = fmaf(v.x, w, a.x); a.y = fmaf(v.y, w, a.y);
    a.z = fmaf(v.z, w, a.z); a.w = fmaf(v.w, w, a.w);
}

// ---------------- 1x1x1 conv: float4 spatial x 4 output channels ----------------
// grid: (SPAT/1024, Cout/4, B), block 256
template <bool RELU, bool AFF>
__global__ __launch_bounds__(256) void k_c1(
    const float* __restrict__ in, const float* __restrict__ w,
    const float* __restrict__ sc, const float* __restrict__ bi,
    float* __restrict__ out, int Cin, int Cout)
{
    int q = blockIdx.x * 256 + threadIdx.x;
    int s = q * 4;
    int o0 = blockIdx.y * 4, b = blockIdx.z;
    const float* ip = in + (size_t)b * Cin * SPAT + s;
    float4 a0 = {0,0,0,0}, a1 = a0, a2 = a0, a3 = a0;
#pragma unroll 4
    for (int c = 0; c < Cin; ++c) {
        float4 v = *(const float4*)(ip + (size_t)c * SPAT);
        fma4(a0, v, w[(o0+0)*Cin + c]);
        fma4(a1, v, w[(o0+1)*Cin + c]);
        fma4(a2, v, w[(o0+2)*Cin + c]);
        fma4(a3, v, w[(o0+3)*Cin + c]);
    }
    float4 accs[4] = {a0, a1, a2, a3};
#pragma unroll
    for (int i = 0; i < 4; ++i) {
        int o = o0 + i;
        float scale = AFF ? sc[o] : 1.f;
        float shift = bi[o];
        float4 r = accs[i];
        r.x = r.x * scale + shift; r.y = r.y * scale + shift;
        r.z = r.z * scale + shift; r.w = r.w * scale + shift;
        if (RELU) {
            r.x = fmaxf(r.x, 0.f); r.y = fmaxf(r.y, 0.f);
            r.z = fmaxf(r.z, 0.f); r.w = fmaxf(r.w, 0.f);
        }
        *(float4*)(out + ((size_t)b * Cout + o) * SPAT + s) = r;
    }
}

// ---------------- depthwise 5x5x5, zero pad 2, + affine, LDS-tiled ----------------
// grid: (8 d-slabs of 4, 32 ch, B), block 256. LDS: 8 planes x 36 rows x 40 cols.
__global__ __launch_bounds__(256) void k_dw5(
    const float* __restrict__ in, const float* __restrict__ w2,
    const float* __restrict__ s2, const float* __restrict__ b2,
    float* __restrict__ out)
{
    __shared__ float lds[8 * 36 * 40];           // 46,080 B
    int tid = threadIdx.x;
    int d0 = blockIdx.x * 4;
    int c = blockIdx.y, b = blockIdx.z;
    const float* ip = in + ((size_t)(b * 32 + c)) * SPAT;

    // zero whole tile (halo stays zero)
    float4 z = {0,0,0,0};
    for (int i = tid; i < 8 * 36 * 40 / 4; i += 256)
        ((float4*)lds)[i] = z;
    __syncthreads();
    // load valid interior planes d0-2 .. d0+5
    for (int i = tid; i < 8 * 256; i += 256) {
        int p = i >> 8, rem = i & 255;
        int r = rem >> 3, c4 = (rem & 7) * 4;
        int d = d0 - 2 + p;
        if (d >= 0 && d < 32) {
            float4 v = *(const float4*)(ip + d * 1024 + r * 32 + c4);
            *(float4*)&lds[p * 1440 + (r + 2) * 40 + (c4 + 4)] = v;
        }
    }
    __syncthreads();

    float scl = s2[c], shf = b2[c];
    const float* wt = w2 + c * 125;
#pragma unroll
    for (int k = 0; k < 4; ++k) {
        int j = tid + k * 256;                   // quad id in slab, 0..1023
        int pd = j >> 8, rem = j & 255;
        int hr = rem >> 3, w4 = (rem & 7) * 4;
        float4 acc = {0,0,0,0};
#pragma unroll
        for (int kd = 0; kd < 5; ++kd) {
            const float* pl = &lds[(pd + kd) * 1440];
#pragma unroll
            for (int kh = 0; kh < 5; ++kh) {
                const float* row = pl + (hr + kh) * 40 + w4;
                float4 r0 = *(const float4*)(row);
                float4 r1 = *(const float4*)(row + 4);
                float4 r2 = *(const float4*)(row + 8);
                float win[12] = {r0.x, r0.y, r0.z, r0.w,
                                 r1.x, r1.y, r1.z, r1.w,
                                 r2.x, r2.y, r2.z, r2.w};
#pragma unroll
                for (int kw = 0; kw < 5; ++kw) {
                    float wv = wt[kd * 25 + kh * 5 + kw];
                    acc.x = fmaf(wv, win[2 + 0 + kw], acc.x);
                    acc.y = fmaf(wv, win[2 + 1 + kw], acc.y);
                    acc.z = fmaf(wv, win[2 + 2 + kw], acc.z);
                    acc.w = fmaf(wv, win[2 + 3 + kw], acc.w);
                }
            }
        }
        acc.x = acc.x * scl + shf; acc.y = acc.y * scl + shf;
        acc.z = acc.z * scl + shf; acc.w = acc.w * scl + shf;
        *(float4*)(out + ((size_t)(b * 32 + c)) * SPAT
                   + (d0 + pd) * 1024 + hr * 32 + w4) = acc;
    }
}

// ---------------- GroupNorm stats, stage 1 (float4) ----------------
__global__ __launch_bounds__(256) void k_gn_part(
    const float* __restrict__ wk, float* __restrict__ partial)
{
    int bg = blockIdx.y;
    const float4* p = (const float4*)(wk + (size_t)bg * 27 * SPAT
                                      + (size_t)blockIdx.x * 16384);
    float sum = 0.f, ss = 0.f;
    for (int i = threadIdx.x; i < 4096; i += 256) {
        float4 v = p[i];
        sum += v.x + v.y + v.z + v.w;
        ss += v.x*v.x + v.y*v.y + v.z*v.z + v.w*v.w;
    }
    __shared__ float sh[512];
    sh[threadIdx.x] = sum; sh[256 + threadIdx.x] = ss;
    __syncthreads();
    for (int off = 128; off > 0; off >>= 1) {
        if (threadIdx.x < off) {
            sh[threadIdx.x] += sh[threadIdx.x + off];
            sh[256 + threadIdx.x] += sh[256 + threadIdx.x + off];
        }
        __syncthreads();
    }
    if (threadIdx.x == 0) {
        partial[(bg * 54 + blockIdx.x) * 2 + 0] = sh[0];
        partial[(bg * 54 + blockIdx.x) * 2 + 1] = sh[256];
    }
}

// ---------------- GroupNorm stats, stage 2 ----------------
__global__ void k_gn_final(const float* __restrict__ partial, float* __restrict__ stats)
{
    int bg = blockIdx.x;
    int t = threadIdx.x;
    float sum = 0.f, ss = 0.f;
    if (t < 54) {
        sum = partial[(bg * 54 + t) * 2 + 0];
        ss  = partial[(bg * 54 + t) * 2 + 1];
    }
#pragma unroll
    for (int off = 32; off > 0; off >>= 1) {
        sum += __shfl_down(sum, off, 64);
        ss  += __shfl_down(ss,  off, 64);
    }
    if (t == 0) {
        stats[bg * 2 + 0] = sum;
        stats[bg * 2 + 1] = ss;
    }
}

// ---------------- SKA: group-major, quad-vectorized ----------------
// grid: (SPAT/1024, 8 groups, B), block 256. Thread: 1 spatial quad x 8 channels.
__global__ __launch_bounds__(256) void k_ska(
    const float* __restrict__ x, const float* __restrict__ wk,
    const float* __restrict__ stats,
    const float* __restrict__ gn_g, const float* __restrict__ gn_b,
    const float* __restrict__ bn_s, const float* __restrict__ bn_b,
    float* __restrict__ y)
{
    int q = blockIdx.x * 256 + threadIdx.x;
    int s = q * 4;
    int g = blockIdx.y, b = blockIdx.z;
    int bg = b * 8 + g;
    const float N = 27.f * (float)SPAT;
    float mu  = stats[bg * 2 + 0] / N;
    float var = stats[bg * 2 + 1] / N - mu * mu;
    float inv = rsqrtf(var + GN_EPS);
    int d = s >> 10, h = (s >> 5) & 31, w0 = s & 31;
    const float* xg = x + ((size_t)(b * 64 + g * 8)) * SPAT;
    const float* wp = wk + ((size_t)(b * 216 + g * 27)) * SPAT + s;

    float4 acc[8];
#pragma unroll
    for (int c = 0; c < 8; ++c) acc[c] = {0,0,0,0};

#pragma unroll
    for (int kd = 0; kd < 3; ++kd) {
        int zd = (d + kd + 31) & 31;
#pragma unroll
        for (int kh = 0; kh < 3; ++kh) {
            int zh = (h + kh + 31) & 31;
            int kbase = (kd * 3 + kh) * 3;
            // normalized kernel values for 3 kw taps, 4 spatial each
            float wn[3][4];
#pragma unroll
            for (int kw = 0; kw < 3; ++kw) {
                int kk = kbase + kw;
                float4 wq = *(const float4*)(wp + (size_t)kk * SPAT);
                float gg = gn_g[g * 27 + kk], gb = gn_b[g * 27 + kk];
                wn[kw][0] = (wq.x - mu) * inv * gg + gb;
                wn[kw][1] = (wq.y - mu) * inv * gg + gb;
                wn[kw][2] = (wq.z - mu) * inv * gg + gb;
                wn[kw][3] = (wq.w - mu) * inv * gg + gb;
            }
            int rowoff = zd * 1024 + zh * 32;
#pragma unroll
            for (int c = 0; c < 8; ++c) {
                const float* row = xg + (size_t)c * SPAT + rowoff;
                float4 m = *(const float4*)(row + w0);
                float xl = row[(w0 + 31) & 31];
                float xr = row[(w0 + 4) & 31];
                float win[6] = {xl, m.x, m.y, m.z, m.w, xr};
#pragma unroll
                for (int kw = 0; kw < 3; ++kw) {
                    acc[c].x = fmaf(win[0 + kw], wn[kw][0], acc[c].x);
                    acc[c].y = fmaf(win[1 + kw], wn[kw][1], acc[c].y);
                    acc[c].z = fmaf(win[2 + kw], wn[kw][2], acc[c].z);
                    acc[c].w = fmaf(win[3 + kw], wn[kw][3], acc[c].w);
                }
            }
        }
    }
#pragma unroll
    for (int c = 0; c < 8; ++c) {
        int ch = g * 8 + c;
        float4 xc = *(const float4*)(xg + (size_t)c * SPAT + s);
        float bs = bn_s[ch], bb = bn_b[ch];
        float4 r;
        r.x = acc[c].x * bs + bb + xc.x;
        r.y = acc[c].y * bs + bb + xc.y;
        r.z = acc[c].z * bs + bb + xc.z;
        r.w = acc[c].w * bs + bb + xc.w;
        *(float4*)(y + ((size_t)(b * 64 + ch)) * SPAT + s) = r;
    }
}

// ---------------- pw2 (128->64) + affine + residual, vectorized ----------------
// grid: (SPAT/1024, 16, B)
__global__ __launch_bounds__(256) void k_pw2_out(
    const float* __restrict__ f1, const float* __restrict__ w,
    const float* __restrict__ sc, const float* __restrict__ bi,
    const float* __restrict__ yres, float* __restrict__ out)
{
    int q = blockIdx.x * 256 + threadIdx.x;
    int s = q * 4;
    int o0 = blockIdx.y * 4, b = blockIdx.z;
    const float* ip = f1 + (size_t)b * 128 * SPAT + s;
    float4 a0 = {0,0,0,0}, a1 = a0, a2 = a0, a3 = a0;
#pragma unroll 4
    for (int c = 0; c < 128; ++c) {
        float4 v = *(const float4*)(ip + (size_t)c * SPAT);
        fma4(a0, v, w[(o0+0)*128 + c]);
        fma4(a1, v, w[(o0+1)*128 + c]);
        fma4(a2, v, w[(o0+2)*128 + c]);
        fma4(a3, v, w[(o0+3)*128 + c]);
    }
    float4 accs[4] = {a0, a1, a2, a3};
#pragma unroll
    for (int i = 0; i < 4; ++i) {
        int o = o0 + i;
        float scale = sc[o], shift = bi[o];
        float4 yv = *(const float4*)(yres + ((size_t)(b * 64 + o)) * SPAT + s);
        float4 r = accs[i];
        r.x = r.x * scale + shift + yv.x;
        r.y = r.y * scale + shift + yv.y;
        r.z = r.z * scale + shift + yv.z;
        r.w = r.w * scale + shift + yv.w;
        *(float4*)(out + ((size_t)(b * 64 + o)) * SPAT + s) = r;
    }
}

extern "C" void kernel_launch(void* const* d_in, const int* in_sizes, int n_in,
                              void* d_out, int out_size, void* d_ws, size_t ws_size,
                              hipStream_t stream)
{
    const float* x     = (const float*)d_in[0];
    const float* w1    = (const float*)d_in[1];
    const float* s1    = (const float*)d_in[2];
    const float* b1    = (const float*)d_in[3];
    const float* w2    = (const float*)d_in[4];
    const float* s2    = (const float*)d_in[5];
    const float* b2    = (const float*)d_in[6];
    const float* w3    = (const float*)d_in[7];
    const float* s3    = (const float*)d_in[8];
    const float* b3    = (const float*)d_in[9];
    const float* w4    = (const float*)d_in[10];
    const float* b4    = (const float*)d_in[11];
    const float* gn_g  = (const float*)d_in[12];
    const float* gn_b  = (const float*)d_in[13];
    const float* bn_s  = (const float*)d_in[14];
    const float* bn_b  = (const float*)d_in[15];
    const float* pw1_w = (const float*)d_in[16];
    const float* pw1_s = (const float*)d_in[17];
    const float* pw1_b = (const float*)d_in[18];
    const float* pw2_w = (const float*)d_in[19];
    const float* pw2_s = (const float*)d_in[20];
    const float* pw2_b = (const float*)d_in[21];

    // Overlapped workspace (~73.4 MB):
    //   region A: [a1 | a2] during LKP, then y during SKA/FFN
    //   region B: wk during cv4..ska, then f1 during FFN
    float* ws    = (float*)d_ws;
    float* a1    = ws;                                   // 2*32*S
    float* a2    = a1 + (size_t)BATCH * 32 * SPAT;       // 2*32*S
    float* yb    = ws;                                   // 2*64*S (over a1+a2)
    float* wkb   = ws + (size_t)BATCH * 64 * SPAT;       // 2*216*S
    float* f1    = wkb;                                  // 2*128*S (over wk)
    float* part  = wkb + (size_t)BATCH * 216 * SPAT;     // 16*54*2
    float* stats = part + 16 * 54 * 2;                   // 32

    dim3 blk(256);
    // cv1 + BN + ReLU : 64 -> 32
    k_c1<true, true><<<dim3(SPAT / 1024, 8, BATCH), blk, 0, stream>>>(
        x, w1, s1, b1, a1, 64, 32);
    // dw 5^3 + BN (LDS-tiled)
    k_dw5<<<dim3(8, 32, BATCH), blk, 0, stream>>>(a1, w2, s2, b2, a2);
    // cv3 + BN + ReLU : 32 -> 32
    k_c1<true, true><<<dim3(SPAT / 1024, 8, BATCH), blk, 0, stream>>>(
        a2, w3, s3, b3, a1, 32, 32);
    // cv4 + bias : 32 -> 216
    k_c1<false, false><<<dim3(SPAT / 1024, 54, BATCH), blk, 0, stream>>>(
        a1, w4, (const float*)nullptr, b4, wkb, 32, 216);
    // GroupNorm stats
    k_gn_part<<<dim3(54, 16, 1), blk, 0, stream>>>(wkb, part);
    k_gn_final<<<dim3(16, 1, 1), dim3(64), 0, stream>>>(part, stats);
    // SKA + BN + residual -> y
    k_ska<<<dim3(SPAT / 1024, 8, BATCH), blk, 0, stream>>>(
        x, wkb, stats, gn_g, gn_b, bn_s, bn_b, yb);
    // pw1 + BN + ReLU : 64 -> 128
    k_c1<true, true><<<dim3(SPAT / 1024, 32, BATCH), blk, 0, stream>>>(
        yb, pw1_w, pw1_s, pw1_b, f1, 64, 128);
    // pw2 + BN + residual -> out
    k_pw2_out<<<dim3(SPAT / 1024, 16, BATCH), blk, 0, stream>>>(
        f1, pw2_w, pw2_s, pw2_b, yb, (float*)d_out);
}

// Round 5
// 231.364 us; speedup vs baseline: 2.0933x; 1.0805x over previous
//
#include <hip/hip_runtime.h>
#include <hip/hip_bf16.h>

#define SPAT 32768   // 32*32*32
#define BATCH 2
#define GN_EPS 1e-5f

__device__ __forceinline__ void fma4(float4& a, const float4& v, float w) {
    a.x = fmaf(v.x, w, a.x); a.y = fmaf(v.y, w, a.y);
    a.z = fmaf(v.z, w, a.z); a.w = fmaf(v.w, w, a.w);
}

// ---------------- 1x1x1 conv: float4 spatial x 4 output channels ----------------
// grid: (SPAT/1024, Cout/4, B), block 256
template <bool RELU, bool AFF>
__global__ __launch_bounds__(256) void k_c1(
    const float* __restrict__ in, const float* __restrict__ w,
    const float* __restrict__ sc, const float* __restrict__ bi,
    float* __restrict__ out, int Cin, int Cout)
{
    int q = blockIdx.x * 256 + threadIdx.x;
    int s = q * 4;
    int o0 = blockIdx.y * 4, b = blockIdx.z;
    const float* ip = in + (size_t)b * Cin * SPAT + s;
    float4 a0 = {0,0,0,0}, a1 = a0, a2 = a0, a3 = a0;
#pragma unroll 4
    for (int c = 0; c < Cin; ++c) {
        float4 v = *(const float4*)(ip + (size_t)c * SPAT);
        fma4(a0, v, w[(o0+0)*Cin + c]);
        fma4(a1, v, w[(o0+1)*Cin + c]);
        fma4(a2, v, w[(o0+2)*Cin + c]);
        fma4(a3, v, w[(o0+3)*Cin + c]);
    }
    float4 accs[4] = {a0, a1, a2, a3};
#pragma unroll
    for (int i = 0; i < 4; ++i) {
        int o = o0 + i;
        float scale = AFF ? sc[o] : 1.f;
        float shift = bi[o];
        float4 r = accs[i];
        r.x = r.x * scale + shift; r.y = r.y * scale + shift;
        r.z = r.z * scale + shift; r.w = r.w * scale + shift;
        if (RELU) {
            r.x = fmaxf(r.x, 0.f); r.y = fmaxf(r.y, 0.f);
            r.z = fmaxf(r.z, 0.f); r.w = fmaxf(r.w, 0.f);
        }
        *(float4*)(out + ((size_t)b * Cout + o) * SPAT + s) = r;
    }
}

// ---------------- cv4 (32->216) + bias, with fused GroupNorm partial stats ----
// grid: (32, 54, B), block 256. partial[((b*216+o)*32 + xblock)*2 + {0,1}]
__global__ __launch_bounds__(256) void k_cv4(
    const float* __restrict__ in, const float* __restrict__ w,
    const float* __restrict__ bi, float* __restrict__ out,
    float* __restrict__ partial)
{
    int q = blockIdx.x * 256 + threadIdx.x;
    int s = q * 4;
    int o0 = blockIdx.y * 4, b = blockIdx.z;
    const float* ip = in + (size_t)b * 32 * SPAT + s;
    float4 a0 = {0,0,0,0}, a1 = a0, a2 = a0, a3 = a0;
#pragma unroll 4
    for (int c = 0; c < 32; ++c) {
        float4 v = *(const float4*)(ip + (size_t)c * SPAT);
        fma4(a0, v, w[(o0+0)*32 + c]);
        fma4(a1, v, w[(o0+1)*32 + c]);
        fma4(a2, v, w[(o0+2)*32 + c]);
        fma4(a3, v, w[(o0+3)*32 + c]);
    }
    float4 accs[4] = {a0, a1, a2, a3};
    float sums[4], sss[4];
#pragma unroll
    for (int i = 0; i < 4; ++i) {
        int o = o0 + i;
        float shift = bi[o];
        float4 r = accs[i];
        r.x += shift; r.y += shift; r.z += shift; r.w += shift;
        *(float4*)(out + ((size_t)b * 216 + o) * SPAT + s) = r;
        sums[i] = r.x + r.y + r.z + r.w;
        sss[i]  = r.x*r.x + r.y*r.y + r.z*r.z + r.w*r.w;
    }
    // wave-level reduce
#pragma unroll
    for (int off = 32; off > 0; off >>= 1) {
#pragma unroll
        for (int i = 0; i < 4; ++i) {
            sums[i] += __shfl_down(sums[i], off, 64);
            sss[i]  += __shfl_down(sss[i],  off, 64);
        }
    }
    __shared__ float sh[4][4][2];
    int wave = threadIdx.x >> 6, lane = threadIdx.x & 63;
    if (lane == 0) {
#pragma unroll
        for (int i = 0; i < 4; ++i) {
            sh[wave][i][0] = sums[i];
            sh[wave][i][1] = sss[i];
        }
    }
    __syncthreads();
    if (threadIdx.x < 4) {
        int i = threadIdx.x;
        float s0 = sh[0][i][0] + sh[1][i][0] + sh[2][i][0] + sh[3][i][0];
        float s1 = sh[0][i][1] + sh[1][i][1] + sh[2][i][1] + sh[3][i][1];
        int o = o0 + i;
        int idx = (((b * 216 + o) * 32) + blockIdx.x) * 2;
        partial[idx + 0] = s0;
        partial[idx + 1] = s1;
    }
}

// ---------------- GN stats stage 2: reduce 27*32 partials per (b,g) ----------------
__global__ __launch_bounds__(256) void k_gn_stats2(
    const float* __restrict__ partial, float* __restrict__ stats)
{
    int bg = blockIdx.x;
    int b = bg >> 3, g = bg & 7;
    float sum = 0.f, ss = 0.f;
    for (int i = threadIdx.x; i < 27 * 32; i += 256) {
        int o = g * 27 + (i >> 5);
        int xb = i & 31;
        int idx = ((b * 216 + o) * 32 + xb) * 2;
        sum += partial[idx + 0];
        ss  += partial[idx + 1];
    }
    __shared__ float sh[512];
    sh[threadIdx.x] = sum; sh[256 + threadIdx.x] = ss;
    __syncthreads();
    for (int off = 128; off > 0; off >>= 1) {
        if (threadIdx.x < off) {
            sh[threadIdx.x] += sh[threadIdx.x + off];
            sh[256 + threadIdx.x] += sh[256 + threadIdx.x + off];
        }
        __syncthreads();
    }
    if (threadIdx.x == 0) {
        stats[bg * 2 + 0] = sh[0];
        stats[bg * 2 + 1] = sh[256];
    }
}

// ---------------- SKA: group-major, quad-vectorized, shuffle wrap ----------------
// grid: (SPAT/1024, 8 groups, B), block 256. Thread: 1 spatial quad x 8 channels.
// 8 consecutive lanes cover one 32-wide row -> circular wrap via __shfl.
__global__ __launch_bounds__(256) void k_ska(
    const float* __restrict__ x, const float* __restrict__ wk,
    const float* __restrict__ stats,
    const float* __restrict__ gn_g, const float* __restrict__ gn_b,
    const float* __restrict__ bn_s, const float* __restrict__ bn_b,
    float* __restrict__ y)
{
    int q = blockIdx.x * 256 + threadIdx.x;
    int s = q * 4;
    int g = blockIdx.y, b = blockIdx.z;
    int bg = b * 8 + g;
    const float N = 27.f * (float)SPAT;
    float mu  = stats[bg * 2 + 0] / N;
    float var = stats[bg * 2 + 1] / N - mu * mu;
    float inv = rsqrtf(var + GN_EPS);
    int d = s >> 10, h = (s >> 5) & 31, w0 = s & 31;
    int lane = threadIdx.x & 63;
    int xl_src = (lane & 56) | ((lane + 7) & 7);   // left neighbor in 8-lane row group
    int xr_src = (lane & 56) | ((lane + 1) & 7);   // right neighbor
    const float* xg = x + ((size_t)(b * 64 + g * 8)) * SPAT;
    const float* wp = wk + ((size_t)(b * 216 + g * 27)) * SPAT + s;

    float4 acc[8];
    float4 xc[8];
#pragma unroll
    for (int c = 0; c < 8; ++c) acc[c] = {0,0,0,0};

#pragma unroll
    for (int kd = 0; kd < 3; ++kd) {
        int zd = (d + kd + 31) & 31;
#pragma unroll
        for (int kh = 0; kh < 3; ++kh) {
            int zh = (h + kh + 31) & 31;
            int kbase = (kd * 3 + kh) * 3;
            float wn[3][4];
#pragma unroll
            for (int kw = 0; kw < 3; ++kw) {
                int kk = kbase + kw;
                float4 wq = *(const float4*)(wp + (size_t)kk * SPAT);
                float gg = gn_g[g * 27 + kk], gb = gn_b[g * 27 + kk];
                wn[kw][0] = (wq.x - mu) * inv * gg + gb;
                wn[kw][1] = (wq.y - mu) * inv * gg + gb;
                wn[kw][2] = (wq.z - mu) * inv * gg + gb;
                wn[kw][3] = (wq.w - mu) * inv * gg + gb;
            }
            int rowoff = zd * 1024 + zh * 32;
            bool center = (kd == 1) && (kh == 1);
#pragma unroll
            for (int c = 0; c < 8; ++c) {
                float4 m = *(const float4*)(xg + (size_t)c * SPAT + rowoff + w0);
                if (center) xc[c] = m;
                float xl = __shfl(m.w, xl_src, 64);
                float xr = __shfl(m.x, xr_src, 64);
                float win[6] = {xl, m.x, m.y, m.z, m.w, xr};
#pragma unroll
                for (int kw = 0; kw < 3; ++kw) {
                    acc[c].x = fmaf(win[0 + kw], wn[kw][0], acc[c].x);
                    acc[c].y = fmaf(win[1 + kw], wn[kw][1], acc[c].y);
                    acc[c].z = fmaf(win[2 + kw], wn[kw][2], acc[c].z);
                    acc[c].w = fmaf(win[3 + kw], wn[kw][3], acc[c].w);
                }
            }
        }
    }
#pragma unroll
    for (int c = 0; c < 8; ++c) {
        int ch = g * 8 + c;
        float bs = bn_s[ch], bb = bn_b[ch];
        float4 r;
        r.x = acc[c].x * bs + bb + xc[c].x;
        r.y = acc[c].y * bs + bb + xc[c].y;
        r.z = acc[c].z * bs + bb + xc[c].z;
        r.w = acc[c].w * bs + bb + xc[c].w;
        *(float4*)(y + ((size_t)(b * 64 + ch)) * SPAT + s) = r;
    }
}

// ---------------- depthwise 5x5x5, zero pad 2, + affine, LDS-tiled ----------------
__global__ __launch_bounds__(256) void k_dw5(
    const float* __restrict__ in, const float* __restrict__ w2,
    const float* __restrict__ s2, const float* __restrict__ b2,
    float* __restrict__ out)
{
    __shared__ float lds[8 * 36 * 40];           // 46,080 B
    int tid = threadIdx.x;
    int d0 = blockIdx.x * 4;
    int c = blockIdx.y, b = blockIdx.z;
    const float* ip = in + ((size_t)(b * 32 + c)) * SPAT;

    float4 z = {0,0,0,0};
    for (int i = tid; i < 8 * 36 * 40 / 4; i += 256)
        ((float4*)lds)[i] = z;
    __syncthreads();
    for (int i = tid; i < 8 * 256; i += 256) {
        int p = i >> 8, rem = i & 255;
        int r = rem >> 3, c4 = (rem & 7) * 4;
        int d = d0 - 2 + p;
        if (d >= 0 && d < 32) {
            float4 v = *(const float4*)(ip + d * 1024 + r * 32 + c4);
            *(float4*)&lds[p * 1440 + (r + 2) * 40 + (c4 + 4)] = v;
        }
    }
    __syncthreads();

    float scl = s2[c], shf = b2[c];
    const float* wt = w2 + c * 125;
#pragma unroll
    for (int k = 0; k < 4; ++k) {
        int j = tid + k * 256;
        int pd = j >> 8, rem = j & 255;
        int hr = rem >> 3, w4 = (rem & 7) * 4;
        float4 acc = {0,0,0,0};
#pragma unroll
        for (int kd = 0; kd < 5; ++kd) {
            const float* pl = &lds[(pd + kd) * 1440];
#pragma unroll
            for (int kh = 0; kh < 5; ++kh) {
                const float* row = pl + (hr + kh) * 40 + w4;
                float4 r0 = *(const float4*)(row);
                float4 r1 = *(const float4*)(row + 4);
                float4 r2 = *(const float4*)(row + 8);
                float win[12] = {r0.x, r0.y, r0.z, r0.w,
                                 r1.x, r1.y, r1.z, r1.w,
                                 r2.x, r2.y, r2.z, r2.w};
#pragma unroll
                for (int kw = 0; kw < 5; ++kw) {
                    float wv = wt[kd * 25 + kh * 5 + kw];
                    acc.x = fmaf(wv, win[2 + 0 + kw], acc.x);
                    acc.y = fmaf(wv, win[2 + 1 + kw], acc.y);
                    acc.z = fmaf(wv, win[2 + 2 + kw], acc.z);
                    acc.w = fmaf(wv, win[2 + 3 + kw], acc.w);
                }
            }
        }
        acc.x = acc.x * scl + shf; acc.y = acc.y * scl + shf;
        acc.z = acc.z * scl + shf; acc.w = acc.w * scl + shf;
        *(float4*)(out + ((size_t)(b * 32 + c)) * SPAT
                   + (d0 + pd) * 1024 + hr * 32 + w4) = acc;
    }
}

// ---------------- pw2 (128->64) + affine + residual, vectorized ----------------
__global__ __launch_bounds__(256) void k_pw2_out(
    const float* __restrict__ f1, const float* __restrict__ w,
    const float* __restrict__ sc, const float* __restrict__ bi,
    const float* __restrict__ yres, float* __restrict__ out)
{
    int q = blockIdx.x * 256 + threadIdx.x;
    int s = q * 4;
    int o0 = blockIdx.y * 4, b = blockIdx.z;
    const float* ip = f1 + (size_t)b * 128 * SPAT + s;
    float4 a0 = {0,0,0,0}, a1 = a0, a2 = a0, a3 = a0;
#pragma unroll 4
    for (int c = 0; c < 128; ++c) {
        float4 v = *(const float4*)(ip + (size_t)c * SPAT);
        fma4(a0, v, w[(o0+0)*128 + c]);
        fma4(a1, v, w[(o0+1)*128 + c]);
        fma4(a2, v, w[(o0+2)*128 + c]);
        fma4(a3, v, w[(o0+3)*128 + c]);
    }
    float4 accs[4] = {a0, a1, a2, a3};
#pragma unroll
    for (int i = 0; i < 4; ++i) {
        int o = o0 + i;
        float scale = sc[o], shift = bi[o];
        float4 yv = *(const float4*)(yres + ((size_t)(b * 64 + o)) * SPAT + s);
        float4 r = accs[i];
        r.x = r.x * scale + shift + yv.x;
        r.y = r.y * scale + shift + yv.y;
        r.z = r.z * scale + shift + yv.z;
        r.w = r.w * scale + shift + yv.w;
        *(float4*)(out + ((size_t)(b * 64 + o)) * SPAT + s) = r;
    }
}

extern "C" void kernel_launch(void* const* d_in, const int* in_sizes, int n_in,
                              void* d_out, int out_size, void* d_ws, size_t ws_size,
                              hipStream_t stream)
{
    const float* x     = (const float*)d_in[0];
    const float* w1    = (const float*)d_in[1];
    const float* s1    = (const float*)d_in[2];
    const float* b1    = (const float*)d_in[3];
    const float* w2    = (const float*)d_in[4];
    const float* s2    = (const float*)d_in[5];
    const float* b2    = (const float*)d_in[6];
    const float* w3    = (const float*)d_in[7];
    const float* s3    = (const float*)d_in[8];
    const float* b3    = (const float*)d_in[9];
    const float* w4    = (const float*)d_in[10];
    const float* b4    = (const float*)d_in[11];
    const float* gn_g  = (const float*)d_in[12];
    const float* gn_b  = (const float*)d_in[13];
    const float* bn_s  = (const float*)d_in[14];
    const float* bn_b  = (const float*)d_in[15];
    const float* pw1_w = (const float*)d_in[16];
    const float* pw1_s = (const float*)d_in[17];
    const float* pw1_b = (const float*)d_in[18];
    const float* pw2_w = (const float*)d_in[19];
    const float* pw2_s = (const float*)d_in[20];
    const float* pw2_b = (const float*)d_in[21];

    // Overlapped workspace (~73.5 MB):
    //   region A: [a1 | a2] during LKP, then y during SKA/FFN
    //   region B: wk during cv4..ska, then f1 during FFN
    float* ws    = (float*)d_ws;
    float* a1    = ws;                                   // 2*32*S
    float* a2    = a1 + (size_t)BATCH * 32 * SPAT;       // 2*32*S
    float* yb    = ws;                                   // 2*64*S (over a1+a2)
    float* wkb   = ws + (size_t)BATCH * 64 * SPAT;       // 2*216*S
    float* f1    = wkb;                                  // 2*128*S (over wk)
    float* part  = wkb + (size_t)BATCH * 216 * SPAT;     // 2*216*32*2
    float* stats = part + BATCH * 216 * 32 * 2;          // 32

    dim3 blk(256);
    // cv1 + BN + ReLU : 64 -> 32
    k_c1<true, true><<<dim3(SPAT / 1024, 8, BATCH), blk, 0, stream>>>(
        x, w1, s1, b1, a1, 64, 32);
    // dw 5^3 + BN (LDS-tiled)
    k_dw5<<<dim3(8, 32, BATCH), blk, 0, stream>>>(a1, w2, s2, b2, a2);
    // cv3 + BN + ReLU : 32 -> 32
    k_c1<true, true><<<dim3(SPAT / 1024, 8, BATCH), blk, 0, stream>>>(
        a2, w3, s3, b3, a1, 32, 32);
    // cv4 + bias + fused GN partial stats : 32 -> 216
    k_cv4<<<dim3(SPAT / 1024, 54, BATCH), blk, 0, stream>>>(
        a1, w4, b4, wkb, part);
    // GN stats stage 2
    k_gn_stats2<<<dim3(16, 1, 1), blk, 0, stream>>>(part, stats);
    // SKA + BN + residual -> y
    k_ska<<<dim3(SPAT / 1024, 8, BATCH), blk, 0, stream>>>(
        x, wkb, stats, gn_g, gn_b, bn_s, bn_b, yb);
    // pw1 + BN + ReLU : 64 -> 128
    k_c1<true, true><<<dim3(SPAT / 1024, 32, BATCH), blk, 0, stream>>>(
        yb, pw1_w, pw1_s, pw1_b, f1, 64, 128);
    // pw2 + BN + residual -> out
    k_pw2_out<<<dim3(SPAT / 1024, 16, BATCH), blk, 0, stream>>>(
        f1, pw2_w, pw2_s, pw2_b, yb, (float*)d_out);
}